// Round 7
// baseline (165.949 us; speedup 1.0000x reference)
//
#include <hip/hip_runtime.h>
#include <hip/hip_bf16.h>

typedef __attribute__((ext_vector_type(8)))  short  bf16x8;
typedef __attribute__((ext_vector_type(4)))  float  f32x4;
typedef __attribute__((ext_vector_type(16))) float  f32x16;
typedef __attribute__((ext_vector_type(4)))  int    i32x4;
typedef __attribute__((ext_vector_type(4)))  unsigned int u32x4;

#define NH   12
#define NKV  2
#define GRP  6
#define HD   128
#define SEQL 4096
#define QD   (NH*HD)
#define KD   (NKV*HD)
#define NT_KV (SEQL/32)     // 128 kv tiles of 32 rows per head
#define TILE_B 8192         // bytes per 32x128 bf16 tile
#define WS_NEED ((size_t)2 * NKV * NT_KV * TILE_B)   // 4 MB: KW + VW

// SCALE * log2(e): softmax in exp2 domain
static constexpr float SCL = 0.08838834764831845f * 1.44269504088896340736f;

static __device__ __forceinline__ unsigned int f2bf(float x) {
    union { __hip_bfloat16 h; unsigned short u; } cv;
    cv.h = __float2bfloat16(x);
    return (unsigned int)cv.u;
}
static __device__ __forceinline__ unsigned int pk2(float x, float y) {
    return f2bf(x) | (f2bf(y) << 16);
}
static __device__ __forceinline__ void gload_lds16(const void* g, void* l) {
    __builtin_amdgcn_global_load_lds(
        (__attribute__((address_space(1))) void*)(g),
        (__attribute__((address_space(3))) void*)(l), 16, 0, 0);
}

// ---- pre-pass: K -> bf16, per-32-row tile, XOR-swizzled (byte ^= (r&7)<<4) ----
__global__ __launch_bounds__(256) void conv_k(const float* __restrict__ K,
                                              char* __restrict__ KW) {
    int id = blockIdx.x*256 + threadIdx.x;      // 131072 threads
    int chunk = id & 15;                         // 16B chunk within 128-d row
    int row   = (id >> 4) & (SEQL-1);
    int kvh   = id >> 16;
    const f32x4* src = reinterpret_cast<const f32x4*>(K + (size_t)row*KD + kvh*HD + chunk*8);
    f32x4 a = src[0], b = src[1];
    bf16x8 t;
    t[0]=(short)f2bf(a[0]); t[1]=(short)f2bf(a[1]); t[2]=(short)f2bf(a[2]); t[3]=(short)f2bf(a[3]);
    t[4]=(short)f2bf(b[0]); t[5]=(short)f2bf(b[1]); t[6]=(short)f2bf(b[2]); t[7]=(short)f2bf(b[3]);
    int tile = row >> 5, r = row & 31;
    int byte = (r*256 + chunk*16) ^ ((r & 7) << 4);
    *reinterpret_cast<bf16x8*>(KW + (size_t)(kvh*NT_KV + tile)*TILE_B + byte) = t;
}

// ---- pre-pass: V -> bf16 in 32x32x16 MFMA B-fragment layout ----
// per 32-row tile (8KB): byte = (d>>5)*2048 + kc*1024 + (d&31)*32 + hi*16 + j*2
// holds V[tile*32 + kc*16 + hi*8 + j][d]
__global__ __launch_bounds__(256) void conv_v(const float* __restrict__ V,
                                              char* __restrict__ VW) {
    int id = blockIdx.x*256 + threadIdx.x;      // 131072 threads
    int d    = id & 127;
    int hi   = (id >> 7) & 1;
    int kc   = (id >> 8) & 1;
    int tile = (id >> 9) & 127;
    int kvh  = id >> 16;
    const float* vp = V + (size_t)(tile*32 + kc*16 + hi*8)*KD + kvh*HD + d;
    bf16x8 t;
    #pragma unroll
    for (int j = 0; j < 8; ++j) t[j] = (short)f2bf(vp[(size_t)j*KD]);
    char* dst = VW + (size_t)(kvh*NT_KV + tile)*TILE_B
              + (d>>5)*2048 + kc*1024 + (d&31)*32 + hi*16;
    *reinterpret_cast<bf16x8*>(dst) = t;
}

// ===================== fast path =====================
// Block = 2 waves on the SAME 32 q-rows; KV tiles split by parity.
// NO in-loop barriers: each wave's private K dbuf ordered by counted vmcnt
// (T4). Waves drift into different phases -> latency hiding. QK chain split
// into 2 accumulators (dep chain 8->4). Merge at end via LDS + 2 barriers.
__global__ __launch_bounds__(128, 3) void gqa_attn_fwd(
        const float* __restrict__ Q,
        const char* __restrict__ KW,
        const char* __restrict__ VW,
        float* __restrict__ O)
{
    __shared__ __align__(16) char kbuf[2][2][8192];   // [wave][dbuf][32x128 bf16 tile]

    const int tid  = threadIdx.x;
    const int wv   = tid >> 6;
    const int lane = tid & 63;
    const int l31  = lane & 31;
    const int hi   = lane >> 5;

    const int bid = blockIdx.x;
    const int h   = bid % NH;
    const int qt  = (SEQL/32 - 1) - bid / NH;   // heavy-first
    const int q0  = qt * 32;
    const int kvh = h / GRP;

    const char* kw0  = KW + (size_t)kvh*NT_KV*TILE_B;
    const char* vw0  = VW + (size_t)kvh*NT_KV*TILE_B;
    const char* ksrc = kw0 + lane*16;

    // ---- Q fragments (B operand): lane holds Q[q0+l31][c*16 + hi*8 + j], prescaled ----
    bf16x8 qf[8];
    {
        const float* qp = Q + (size_t)(q0 + l31)*QD + h*HD + hi*8;
        #pragma unroll
        for (int c = 0; c < 8; ++c) {
            const f32x4* p4 = reinterpret_cast<const f32x4*>(qp + c*16);
            f32x4 a = p4[0], b = p4[1];
            bf16x8 f;
            f[0]=(short)f2bf(a[0]*SCL); f[1]=(short)f2bf(a[1]*SCL);
            f[2]=(short)f2bf(a[2]*SCL); f[3]=(short)f2bf(a[3]*SCL);
            f[4]=(short)f2bf(b[0]*SCL); f[5]=(short)f2bf(b[1]*SCL);
            f[6]=(short)f2bf(b[2]*SCL); f[7]=(short)f2bf(b[3]*SCL);
            qf[c] = f;
        }
    }

    f32x16 oa[4];
    #pragma unroll
    for (int dc = 0; dc < 4; ++dc)
        #pragma unroll
        for (int r = 0; r < 16; ++r) oa[dc][r] = 0.f;
    float m_run = -1e30f, lsum = 0.f;   // per-lane HALF-sum for q = l31 (hi splits kv rows)

    const int vlocal = l31*32 + hi*16;

    // prologue: stage this wave's first tile into its buf 0 (if it has one)
    if (wv <= qt) {
        #pragma unroll
        for (int i = 0; i < 8; ++i)
            gload_lds16(ksrc + (size_t)wv*TILE_B + i*1024, &kbuf[wv][0][i*1024]);
    }

    int cur = 0;
    for (int t = wv; t <= qt; t += 2, cur ^= 1) {
        // ---- V loads for tile t: direct global->reg (L2-resident), coalesced ----
        const char* vt = vw0 + (size_t)t*TILE_B + vlocal;
        bf16x8 vf[4][2];
        #pragma unroll
        for (int dc = 0; dc < 4; ++dc)
            #pragma unroll
            for (int kc = 0; kc < 2; ++kc)
                vf[dc][kc] = *reinterpret_cast<const bf16x8*>(vt + dc*2048 + kc*1024);

        // ---- prefetch next K tile into other buffer, then counted wait for K(t) ----
        const int nxt = t + 2;
        if (nxt <= qt) {
            #pragma unroll
            for (int j = 0; j < 8; ++j)
                gload_lds16(ksrc + (size_t)nxt*TILE_B + j*1024, &kbuf[wv][cur^1][j*1024]);
            // newer-than-K(t): 8 V loads + 8 prefetch -> wait until only those remain
            asm volatile("s_waitcnt vmcnt(16)" ::: "memory");
        } else {
            asm volatile("s_waitcnt vmcnt(8)" ::: "memory");
        }
        __builtin_amdgcn_sched_barrier(0);

        // ---- QK^T: S^T[kv][q], lane = one q column; 2 split chains ----
        f32x16 sA, sB;
        #pragma unroll
        for (int r = 0; r < 16; ++r) { sA[r] = 0.f; sB[r] = 0.f; }
        const char* kb = &kbuf[wv][cur][0];
        __builtin_amdgcn_s_setprio(1);
        #pragma unroll
        for (int c = 0; c < 4; ++c) {
            const int offA = (l31*256 + c*32 + hi*16) ^ ((l31 & 7) << 4);
            const int offB = (l31*256 + (c+4)*32 + hi*16) ^ ((l31 & 7) << 4);
            bf16x8 kfA = *reinterpret_cast<const bf16x8*>(kb + offA);
            bf16x8 kfB = *reinterpret_cast<const bf16x8*>(kb + offB);
            sA = __builtin_amdgcn_mfma_f32_32x32x16_bf16(kfA, qf[c],   sA, 0, 0, 0);
            sB = __builtin_amdgcn_mfma_f32_32x32x16_bf16(kfB, qf[c+4], sB, 0, 0, 0);
        }
        __builtin_amdgcn_s_setprio(0);
        f32x16 s;
        #pragma unroll
        for (int r = 0; r < 16; ++r) s[r] = sA[r] + sB[r];

        // ---- causal mask (diagonal tile only) ----
        if (t == qt) {
            const int qabs = q0 + l31;
            #pragma unroll
            for (int r = 0; r < 16; ++r) {
                const int kvi = q0 + (r&3) + 8*(r>>2) + 4*hi;
                if (kvi > qabs) s[r] = -1e30f;
            }
        }

        // ---- online softmax (defer-max, THR=8) ----
        float pmax = s[0];
        #pragma unroll
        for (int r = 1; r < 16; ++r) pmax = fmaxf(pmax, s[r]);
        pmax = fmaxf(pmax, __shfl_xor(pmax, 32));   // combine halves: m consistent

        if (__ballot(pmax > m_run + 8.0f)) {
            const float mnew  = fmaxf(m_run, pmax);
            const float alpha = exp2f(m_run - mnew);
            m_run = mnew;
            lsum *= alpha;
            #pragma unroll
            for (int r = 0; r < 16; ++r) {
                const float ar = __shfl(alpha, (r&3) + 8*(r>>2) + 4*hi, 64);
                #pragma unroll
                for (int dc = 0; dc < 4; ++dc) oa[dc][r] *= ar;
            }
        }

        float p[16]; float ps = 0.f;
        #pragma unroll
        for (int r = 0; r < 16; ++r) { p[r] = exp2f(s[r] - m_run); ps += p[r]; }
        lsum += ps;

        // ---- P -> A-fragment: pack pairs, half-wave exchange via permlane32_swap ----
        unsigned w0, w1, w2, w3, w4, w5, w6, w7;
        {
            unsigned a = pk2(p[0],  p[1]),  b = pk2(p[4],  p[5]);
            auto r0 = __builtin_amdgcn_permlane32_swap(a, b, false, false);
            w0 = r0[0]; w2 = r0[1];
            unsigned c2 = pk2(p[2],  p[3]),  d2 = pk2(p[6],  p[7]);
            auto r1 = __builtin_amdgcn_permlane32_swap(c2, d2, false, false);
            w1 = r1[0]; w3 = r1[1];
            unsigned e = pk2(p[8],  p[9]),  f = pk2(p[12], p[13]);
            auto r2 = __builtin_amdgcn_permlane32_swap(e, f, false, false);
            w4 = r2[0]; w6 = r2[1];
            unsigned g = pk2(p[10], p[11]), hh = pk2(p[14], p[15]);
            auto r3 = __builtin_amdgcn_permlane32_swap(g, hh, false, false);
            w5 = r3[0]; w7 = r3[1];
        }
        const bf16x8 pa0 = __builtin_bit_cast(bf16x8, (u32x4){w0, w1, w2, w3});
        const bf16x8 pa1 = __builtin_bit_cast(bf16x8, (u32x4){w4, w5, w6, w7});

        // ---- PV: O[32 q][128 d] += P[32][32] * V[32][128] ----
        __builtin_amdgcn_s_setprio(1);
        #pragma unroll
        for (int dc = 0; dc < 4; ++dc) {
            oa[dc] = __builtin_amdgcn_mfma_f32_32x32x16_bf16(pa0, vf[dc][0], oa[dc], 0, 0, 0);
            oa[dc] = __builtin_amdgcn_mfma_f32_32x32x16_bf16(pa1, vf[dc][1], oa[dc], 0, 0, 0);
        }
        __builtin_amdgcn_s_setprio(0);
    }

    // ---- combine the two kv-row halves of lsum ----
    lsum += __shfl_xor(lsum, 32);

    // ---- flash-merge of the two waves' partials (kbuf reused; barrier-guarded) ----
    float* cO = reinterpret_cast<float*>(&kbuf[1][0][0]);   // 16 KB: O'[32][128]
    float* cm = reinterpret_cast<float*>(&kbuf[0][0][0]);   // m[32], l[32]

    __syncthreads();   // both waves done with their loop reads/DMA of kbuf
    if (wv == 1) {
        if (hi == 0) { cm[l31] = m_run; cm[32 + l31] = lsum; }
        #pragma unroll
        for (int r = 0; r < 16; ++r) {
            const int qr = (r&3) + 8*(r>>2) + 4*hi;
            #pragma unroll
            for (int dc = 0; dc < 4; ++dc)
                cO[qr*128 + dc*32 + l31] = oa[dc][r];
        }
    }
    __syncthreads();
    if (wv == 0) {
        const float m1 = cm[l31], l1 = cm[32 + l31];
        const float M  = fmaxf(m_run, m1);
        const float a0 = exp2f(m_run - M);
        const float a1 = exp2f(m1 - M);
        const float inv = 1.0f / (lsum*a0 + l1*a1);
        #pragma unroll
        for (int r = 0; r < 16; ++r) {
            const int qr = (r&3) + 8*(r>>2) + 4*hi;
            const float a0r = __shfl(a0, qr, 64);
            const float a1r = __shfl(a1, qr, 64);
            const float ivr = __shfl(inv, qr, 64);
            float* op = O + (size_t)(q0 + qr)*QD + h*HD + l31;
            #pragma unroll
            for (int dc = 0; dc < 4; ++dc) {
                const float merged = oa[dc][r]*a0r + cO[qr*128 + dc*32 + l31]*a1r;
                op[dc*32] = merged * ivr;
            }
        }
    }
}

// ===================== fallback: self-staging (no workspace), verified R1 =====================
__global__ __launch_bounds__(256) void gqa_attn_fwd_fb(
        const float* __restrict__ Q, const float* __restrict__ K,
        const float* __restrict__ V, float* __restrict__ O)
{
    __shared__ unsigned short K_lds[32*128];
    __shared__ unsigned short V_lds[32*128];

    const int tid  = threadIdx.x;
    const int wv   = tid >> 6;
    const int lane = tid & 63;
    const int lo   = lane & 15;
    const int g    = lane >> 4;

    const int bid = blockIdx.x;
    const int h   = bid % NH;
    const int qt  = (SEQL/64 - 1) - bid / NH;
    const int q0  = qt * 64;
    const int kvh = h / GRP;

    bf16x8 qf[4];
    {
        const int qrow = q0 + wv*16 + lo;
        const float* qp = Q + (size_t)qrow*QD + h*HD + g*8;
        #pragma unroll
        for (int c = 0; c < 4; ++c) {
            const f32x4* p = reinterpret_cast<const f32x4*>(qp + c*32);
            f32x4 a = p[0], b = p[1];
            bf16x8 f;
            f[0]=(short)f2bf(a[0]*SCL); f[1]=(short)f2bf(a[1]*SCL);
            f[2]=(short)f2bf(a[2]*SCL); f[3]=(short)f2bf(a[3]*SCL);
            f[4]=(short)f2bf(b[0]*SCL); f[5]=(short)f2bf(b[1]*SCL);
            f[6]=(short)f2bf(b[2]*SCL); f[7]=(short)f2bf(b[3]*SCL);
            qf[c] = f;
        }
    }

    f32x4 oa[8];
    #pragma unroll
    for (int i = 0; i < 8; ++i) oa[i] = (f32x4){0.f, 0.f, 0.f, 0.f};
    float m_run = -1e30f, lsum = 0.f;

    const int qmax_w = q0 + wv*16 + 15;
    const int nt = q0/32 + 2;

    for (int t = 0; t < nt; ++t) {
        const int kvb = t*32;
        __syncthreads();
        {
            const int row = tid >> 3;
            const int dc  = (tid & 7) * 16;
            const float* kp = K + (size_t)(kvb+row)*KD + kvh*HD + dc;
            const f32x4* kp4 = reinterpret_cast<const f32x4*>(kp);
            f32x4 a0 = kp4[0], a1 = kp4[1], a2 = kp4[2], a3 = kp4[3];
            bf16x8 t0, t1;
            t0[0]=(short)f2bf(a0[0]); t0[1]=(short)f2bf(a0[1]); t0[2]=(short)f2bf(a0[2]); t0[3]=(short)f2bf(a0[3]);
            t0[4]=(short)f2bf(a1[0]); t0[5]=(short)f2bf(a1[1]); t0[6]=(short)f2bf(a1[2]); t0[7]=(short)f2bf(a1[3]);
            t1[0]=(short)f2bf(a2[0]); t1[1]=(short)f2bf(a2[1]); t1[2]=(short)f2bf(a2[2]); t1[3]=(short)f2bf(a2[3]);
            t1[4]=(short)f2bf(a3[0]); t1[5]=(short)f2bf(a3[1]); t1[6]=(short)f2bf(a3[2]); t1[7]=(short)f2bf(a3[3]);
            char* kl = reinterpret_cast<char*>(K_lds);
            const int byte = row*256 + dc*2;
            const int swzw = (row & 7) << 4;
            *reinterpret_cast<bf16x8*>(kl + ((byte)      ^ swzw)) = t0;
            *reinterpret_cast<bf16x8*>(kl + ((byte + 16) ^ swzw)) = t1;
        }
        {
            const int kv0   = (tid >> 4) * 2;
            const int dbase = (tid & 15) * 8;
            const float* vp = V + (size_t)(kvb+kv0)*KD + kvh*HD + dbase;
            const f32x4* v0 = reinterpret_cast<const f32x4*>(vp);
            const f32x4* v1 = reinterpret_cast<const f32x4*>(vp + KD);
            f32x4 a0 = v0[0], a1 = v0[1], b0 = v1[0], b1 = v1[1];
            unsigned int* vf = reinterpret_cast<unsigned int*>(V_lds);
            #pragma unroll
            for (int i = 0; i < 8; ++i) {
                float x0 = (i < 4) ? a0[i] : a1[i-4];
                float x1 = (i < 4) ? b0[i] : b1[i-4];
                unsigned int pkv = f2bf(x0) | (f2bf(x1) << 16);
                const int d  = dbase + i;
                const int db = d >> 4, dl = d & 15;
                const int slot = (kv0 >> 3) ^ (d & 3) ^ (db & 3);
                const int byte = db*1024 + dl*64 + slot*16 + (kv0 & 7)*2;
                vf[byte >> 2] = pkv;
            }
        }
        __syncthreads();

        if (kvb > qmax_w) continue;

        f32x4 s0 = {0,0,0,0}, s1 = {0,0,0,0};
        {
            const char* kl = reinterpret_cast<const char*>(K_lds);
            const int r0 = lo, r1 = lo + 16;
            const int sw0 = (r0 & 7) << 4, sw1 = (r1 & 7) << 4;
            #pragma unroll
            for (int c = 0; c < 4; ++c) {
                bf16x8 ka = *reinterpret_cast<const bf16x8*>(kl + ((r0*256 + c*64 + g*16) ^ sw0));
                bf16x8 kb = *reinterpret_cast<const bf16x8*>(kl + ((r1*256 + c*64 + g*16) ^ sw1));
                s0 = __builtin_amdgcn_mfma_f32_16x16x32_bf16(ka, qf[c], s0, 0, 0, 0);
                s1 = __builtin_amdgcn_mfma_f32_16x16x32_bf16(kb, qf[c], s1, 0, 0, 0);
            }
        }

        const int qabs = q0 + wv*16 + lo;
        if (kvb + 31 > q0 + wv*16) {
            #pragma unroll
            for (int r = 0; r < 4; ++r) {
                if (kvb + 4*g + r      > qabs) s0[r] = -1e30f;
                if (kvb + 16 + 4*g + r > qabs) s1[r] = -1e30f;
            }
        }

        float pmax = fmaxf(fmaxf(fmaxf(s0[0],s0[1]), fmaxf(s0[2],s0[3])),
                           fmaxf(fmaxf(s1[0],s1[1]), fmaxf(s1[2],s1[3])));
        pmax = fmaxf(pmax, __shfl_xor(pmax, 16));
        pmax = fmaxf(pmax, __shfl_xor(pmax, 32));
        const float m_new = fmaxf(m_run, pmax);
        const float alpha = exp2f(m_run - m_new);
        float p0[4], p1[4];
        float psum = 0.f;
        #pragma unroll
        for (int r = 0; r < 4; ++r) {
            p0[r] = exp2f(s0[r] - m_new); psum += p0[r];
            p1[r] = exp2f(s1[r] - m_new); psum += p1[r];
        }
        psum += __shfl_xor(psum, 16);
        psum += __shfl_xor(psum, 32);
        lsum = lsum * alpha + psum;
        m_run = m_new;

        unsigned int pk0[2], pk1[2];
        pk0[0] = f2bf(p0[0]) | (f2bf(p0[1]) << 16);
        pk0[1] = f2bf(p0[2]) | (f2bf(p0[3]) << 16);
        pk1[0] = f2bf(p1[0]) | (f2bf(p1[1]) << 16);
        pk1[1] = f2bf(p1[2]) | (f2bf(p1[3]) << 16);

        i32x4 pav;
        #pragma unroll
        for (int pp = 0; pp < 4; ++pp) {
            const int src = lo + ((2*g + (pp >> 1)) & 3) * 16;
            const int v0s = __shfl((int)pk0[pp & 1], src, 64);
            const int v1s = __shfl((int)pk1[pp & 1], src, 64);
            pav[pp] = (g < 2) ? v0s : v1s;
        }
        const bf16x8 paf = __builtin_bit_cast(bf16x8, pav);

        float al[4];
        #pragma unroll
        for (int r = 0; r < 4; ++r) al[r] = __shfl(alpha, 4*g + r, 64);
        #pragma unroll
        for (int db = 0; db < 8; ++db) {
            oa[db][0] *= al[0]; oa[db][1] *= al[1];
            oa[db][2] *= al[2]; oa[db][3] *= al[3];
        }

        const char* vl = reinterpret_cast<const char*>(V_lds);
        #pragma unroll
        for (int db = 0; db < 8; ++db) {
            const int slot = g ^ (lo & 3) ^ (db & 3);
            bf16x8 vfr = *reinterpret_cast<const bf16x8*>(vl + db*1024 + lo*64 + slot*16);
            oa[db] = __builtin_amdgcn_mfma_f32_16x16x32_bf16(paf, vfr, oa[db], 0, 0, 0);
        }
    }

    float li[4];
    #pragma unroll
    for (int r = 0; r < 4; ++r) li[r] = 1.0f / __shfl(lsum, 4*g + r, 64);
    #pragma unroll
    for (int db = 0; db < 8; ++db) {
        #pragma unroll
        for (int r = 0; r < 4; ++r) {
            O[(size_t)(q0 + wv*16 + 4*g + r)*QD + h*HD + db*16 + lo] = oa[db][r] * li[r];
        }
    }
}

extern "C" void kernel_launch(void* const* d_in, const int* in_sizes, int n_in,
                              void* d_out, int out_size, void* d_ws, size_t ws_size,
                              hipStream_t stream) {
    const float* q = (const float*)d_in[0];
    const float* k = (const float*)d_in[1];
    const float* v = (const float*)d_in[2];
    float* out = (float*)d_out;
    (void)in_sizes; (void)n_in; (void)out_size;

    if (ws_size >= WS_NEED && d_ws != nullptr) {
        char* kw = (char*)d_ws;
        char* vw = kw + (size_t)NKV * NT_KV * TILE_B;
        conv_k<<<dim3(512), dim3(256), 0, stream>>>(k, kw);
        conv_v<<<dim3(512), dim3(256), 0, stream>>>(v, vw);
        gqa_attn_fwd<<<dim3((SEQL/32)*NH), dim3(128), 0, stream>>>(q, kw, vw, out);
    } else {
        gqa_attn_fwd_fb<<<dim3((SEQL/64)*NH), dim3(256), 0, stream>>>(q, k, v, out);
    }
}

// Round 8
// 104.955 us; speedup vs baseline: 1.5811x; 1.5811x over previous
//
#include <hip/hip_runtime.h>
#include <hip/hip_bf16.h>

typedef __attribute__((ext_vector_type(8)))  short  bf16x8;
typedef __attribute__((ext_vector_type(4)))  float  f32x4;
typedef __attribute__((ext_vector_type(16))) float  f32x16;
typedef __attribute__((ext_vector_type(4)))  int    i32x4;
typedef __attribute__((ext_vector_type(4)))  unsigned int u32x4;

#define NH   12
#define NKV  2
#define GRP  6
#define HD   128
#define SEQL 4096
#define QD   (NH*HD)
#define KD   (NKV*HD)
#define NT_KV (SEQL/32)     // 128 kv tiles of 32 rows per head
#define TILE_B 8192         // bytes per 32x128 bf16 tile
#define WS_NEED ((size_t)2 * NKV * NT_KV * TILE_B)   // 4 MB: KW + VW

// SCALE * log2(e): softmax in exp2 domain
static constexpr float SCL = 0.08838834764831845f * 1.44269504088896340736f;

static __device__ __forceinline__ unsigned int f2bf(float x) {
    union { __hip_bfloat16 h; unsigned short u; } cv;
    cv.h = __float2bfloat16(x);
    return (unsigned int)cv.u;
}
static __device__ __forceinline__ unsigned int pk2(float x, float y) {
    return f2bf(x) | (f2bf(y) << 16);
}

// ---- pre-pass: K -> bf16 in QK A-fragment order ----
// per 32-row tile (8KB): addr = c*1024 + lane*16, lane = hi*32+l31,
// holding K[tile*32 + l31][c*16 + hi*8 + j]  (j=0..7)
// -> main kernel K reads are fully-coalesced 1KB wave loads, no LDS needed.
__global__ __launch_bounds__(256) void conv_k(const float* __restrict__ K,
                                              char* __restrict__ KW) {
    int id = blockIdx.x*256 + threadIdx.x;      // 131072 threads
    int l31  = id & 31;
    int hi   = (id >> 5) & 1;
    int c    = (id >> 6) & 7;
    int tile = (id >> 9) & 127;
    int kvh  = id >> 16;
    const float* src = K + (size_t)(tile*32 + l31)*KD + kvh*HD + c*16 + hi*8;
    const f32x4* s4 = reinterpret_cast<const f32x4*>(src);
    f32x4 a = s4[0], b = s4[1];
    bf16x8 t;
    t[0]=(short)f2bf(a[0]); t[1]=(short)f2bf(a[1]); t[2]=(short)f2bf(a[2]); t[3]=(short)f2bf(a[3]);
    t[4]=(short)f2bf(b[0]); t[5]=(short)f2bf(b[1]); t[6]=(short)f2bf(b[2]); t[7]=(short)f2bf(b[3]);
    *reinterpret_cast<bf16x8*>(KW + (size_t)(kvh*NT_KV + tile)*TILE_B
                               + c*1024 + (hi*32 + l31)*16) = t;
}

// ---- pre-pass: V -> bf16 in 32x32x16 MFMA B-fragment layout ----
// per 32-row tile (8KB): byte = (d>>5)*2048 + kc*1024 + (d&31)*32 + hi*16 + j*2
// holds V[tile*32 + kc*16 + hi*8 + j][d]
__global__ __launch_bounds__(256) void conv_v(const float* __restrict__ V,
                                              char* __restrict__ VW) {
    int id = blockIdx.x*256 + threadIdx.x;      // 131072 threads
    int d    = id & 127;
    int hi   = (id >> 7) & 1;
    int kc   = (id >> 8) & 1;
    int tile = (id >> 9) & 127;
    int kvh  = id >> 16;
    const float* vp = V + (size_t)(tile*32 + kc*16 + hi*8)*KD + kvh*HD + d;
    bf16x8 t;
    #pragma unroll
    for (int j = 0; j < 8; ++j) t[j] = (short)f2bf(vp[(size_t)j*KD]);
    char* dst = VW + (size_t)(kvh*NT_KV + tile)*TILE_B
              + (d>>5)*2048 + kc*1024 + (d&31)*32 + hi*16;
    *reinterpret_cast<bf16x8*>(dst) = t;
}

// ===================== fast path =====================
// Block = 2 waves on the SAME 32 q-rows; KV tiles split by parity.
// ZERO LDS in the main loop: K pre-laid-out in A-fragment order, direct
// global->reg, register-double-buffered one iteration ahead (manual 2x
// unroll, named sets). V direct global->reg at compute start. All waitcnts
// compiler-managed. LDS only for the final 2-wave flash-merge.
__global__ __launch_bounds__(128, 2) void gqa_attn_fwd(
        const float* __restrict__ Q,
        const char* __restrict__ KW,
        const char* __restrict__ VW,
        float* __restrict__ O)
{
    __shared__ float cO[32*128];   // merge buffer: O'[32][128]
    __shared__ float cm[64];       // m[32], l[32]

    const int tid  = threadIdx.x;
    const int wv   = tid >> 6;
    const int lane = tid & 63;
    const int l31  = lane & 31;
    const int hi   = lane >> 5;

    const int bid = blockIdx.x;
    const int h   = bid % NH;
    const int qt  = (SEQL/32 - 1) - bid / NH;   // heavy-first
    const int q0  = qt * 32;
    const int kvh = h / GRP;

    const char* kw0 = KW + (size_t)kvh*NT_KV*TILE_B;
    const char* vw0 = VW + (size_t)kvh*NT_KV*TILE_B;
    const int klocal = lane*16;
    const int vlocal = l31*32 + hi*16;

    // ---- Q fragments (B operand): lane holds Q[q0+l31][c*16 + hi*8 + j], prescaled ----
    bf16x8 qf[8];
    {
        const float* qp = Q + (size_t)(q0 + l31)*QD + h*HD + hi*8;
        #pragma unroll
        for (int c = 0; c < 8; ++c) {
            const f32x4* p4 = reinterpret_cast<const f32x4*>(qp + c*16);
            f32x4 a = p4[0], b = p4[1];
            bf16x8 f;
            f[0]=(short)f2bf(a[0]*SCL); f[1]=(short)f2bf(a[1]*SCL);
            f[2]=(short)f2bf(a[2]*SCL); f[3]=(short)f2bf(a[3]*SCL);
            f[4]=(short)f2bf(b[0]*SCL); f[5]=(short)f2bf(b[1]*SCL);
            f[6]=(short)f2bf(b[2]*SCL); f[7]=(short)f2bf(b[3]*SCL);
            qf[c] = f;
        }
    }

    f32x16 oa[4];
    #pragma unroll
    for (int dc = 0; dc < 4; ++dc)
        #pragma unroll
        for (int r = 0; r < 16; ++r) oa[dc][r] = 0.f;
    float m_run = -1e30f, lsum = 0.f;   // per-lane HALF-sum for q=l31 (hi splits kv rows)

    auto loadK = [&](int tt, bf16x8 (&kf)[8]) {
        const char* kt = kw0 + (size_t)tt*TILE_B + klocal;
        #pragma unroll
        for (int c = 0; c < 8; ++c)
            kf[c] = *reinterpret_cast<const bf16x8*>(kt + c*1024);
    };

    auto body = [&](int tcur, const bf16x8 (&kf)[8]) {
        // V loads issued first, consumed at PV (~400cy later) -> latency hidden
        const char* vt = vw0 + (size_t)tcur*TILE_B + vlocal;
        bf16x8 vf[8];
        #pragma unroll
        for (int i = 0; i < 8; ++i)
            vf[i] = *reinterpret_cast<const bf16x8*>(vt + (i>>1)*2048 + (i&1)*1024);

        // ---- QK^T: S^T[kv][q], lane = one q column; 2 split chains ----
        f32x16 sA, sB;
        #pragma unroll
        for (int r = 0; r < 16; ++r) { sA[r] = 0.f; sB[r] = 0.f; }
        __builtin_amdgcn_s_setprio(1);
        #pragma unroll
        for (int c = 0; c < 4; ++c) {
            sA = __builtin_amdgcn_mfma_f32_32x32x16_bf16(kf[c],   qf[c],   sA, 0, 0, 0);
            sB = __builtin_amdgcn_mfma_f32_32x32x16_bf16(kf[c+4], qf[c+4], sB, 0, 0, 0);
        }
        __builtin_amdgcn_s_setprio(0);
        f32x16 s;
        #pragma unroll
        for (int r = 0; r < 16; ++r) s[r] = sA[r] + sB[r];

        // ---- causal mask (diagonal tile only) ----
        if (tcur == qt) {
            const int qabs = q0 + l31;
            #pragma unroll
            for (int r = 0; r < 16; ++r) {
                const int kvi = q0 + (r&3) + 8*(r>>2) + 4*hi;
                if (kvi > qabs) s[r] = -1e30f;
            }
        }

        // ---- online softmax (defer-max, THR=8); pairwise max tree ----
        float m0 = fmaxf(s[0],s[1]),  m1 = fmaxf(s[2],s[3]);
        float m2 = fmaxf(s[4],s[5]),  m3 = fmaxf(s[6],s[7]);
        float m4 = fmaxf(s[8],s[9]),  m5 = fmaxf(s[10],s[11]);
        float m6 = fmaxf(s[12],s[13]), m7 = fmaxf(s[14],s[15]);
        m0 = fmaxf(m0,m1); m2 = fmaxf(m2,m3); m4 = fmaxf(m4,m5); m6 = fmaxf(m6,m7);
        float pmax = fmaxf(fmaxf(m0,m2), fmaxf(m4,m6));
        pmax = fmaxf(pmax, __shfl_xor(pmax, 32));   // halves agree on m

        if (__ballot(pmax > m_run + 8.0f)) {
            const float mnew  = fmaxf(m_run, pmax);
            const float alpha = exp2f(m_run - mnew);
            m_run = mnew;
            lsum *= alpha;
            #pragma unroll
            for (int r = 0; r < 16; ++r) {
                const float ar = __shfl(alpha, (r&3) + 8*(r>>2) + 4*hi, 64);
                #pragma unroll
                for (int dc = 0; dc < 4; ++dc) oa[dc][r] *= ar;
            }
        }

        // p overwrites s; two partial sums to shorten the add chain
        float ps0 = 0.f, ps1 = 0.f;
        #pragma unroll
        for (int r = 0; r < 16; r += 2) {
            s[r]   = exp2f(s[r]   - m_run); ps0 += s[r];
            s[r+1] = exp2f(s[r+1] - m_run); ps1 += s[r+1];
        }
        lsum += ps0 + ps1;

        // ---- P -> A-fragment: pack pairs, half-wave exchange via permlane32_swap ----
        unsigned w0, w1, w2, w3, w4, w5, w6, w7;
        {
            unsigned a = pk2(s[0],  s[1]),  b = pk2(s[4],  s[5]);
            auto r0 = __builtin_amdgcn_permlane32_swap(a, b, false, false);
            w0 = r0[0]; w2 = r0[1];
            unsigned c2 = pk2(s[2],  s[3]),  d2 = pk2(s[6],  s[7]);
            auto r1 = __builtin_amdgcn_permlane32_swap(c2, d2, false, false);
            w1 = r1[0]; w3 = r1[1];
            unsigned e = pk2(s[8],  s[9]),  f = pk2(s[12], s[13]);
            auto r2 = __builtin_amdgcn_permlane32_swap(e, f, false, false);
            w4 = r2[0]; w6 = r2[1];
            unsigned g = pk2(s[10], s[11]), hh = pk2(s[14], s[15]);
            auto r3 = __builtin_amdgcn_permlane32_swap(g, hh, false, false);
            w5 = r3[0]; w7 = r3[1];
        }
        const bf16x8 pa0 = __builtin_bit_cast(bf16x8, (u32x4){w0, w1, w2, w3});
        const bf16x8 pa1 = __builtin_bit_cast(bf16x8, (u32x4){w4, w5, w6, w7});

        // ---- PV: O[32 q][128 d] += P[32][32] * V[32][128] ----
        __builtin_amdgcn_s_setprio(1);
        #pragma unroll
        for (int dc = 0; dc < 4; ++dc) {
            oa[dc] = __builtin_amdgcn_mfma_f32_32x32x16_bf16(pa0, vf[dc*2],   oa[dc], 0, 0, 0);
            oa[dc] = __builtin_amdgcn_mfma_f32_32x32x16_bf16(pa1, vf[dc*2+1], oa[dc], 0, 0, 0);
        }
        __builtin_amdgcn_s_setprio(0);
    };

    // ---- main loop: manual 2x unroll, named K register sets (rule #20) ----
    bf16x8 kfA[8], kfB[8];
    int t = wv;                      // this wave's tiles: wv, wv+2, ...
    if (t <= qt) loadK(t, kfA);
    while (t <= qt) {
        if (t + 2 <= qt) loadK(t + 2, kfB);
        body(t, kfA);
        t += 2;
        if (t > qt) break;
        if (t + 2 <= qt) loadK(t + 2, kfA);
        body(t, kfB);
        t += 2;
    }

    // ---- combine the two kv-row halves of lsum ----
    lsum += __shfl_xor(lsum, 32);

    // ---- flash-merge of the two waves' partials (single barrier) ----
    if (wv == 1) {
        if (hi == 0) { cm[l31] = m_run; cm[32 + l31] = lsum; }
        #pragma unroll
        for (int r = 0; r < 16; ++r) {
            const int qr = (r&3) + 8*(r>>2) + 4*hi;
            #pragma unroll
            for (int dc = 0; dc < 4; ++dc)
                cO[qr*128 + dc*32 + l31] = oa[dc][r];
        }
    }
    __syncthreads();
    if (wv == 0) {
        const float m1 = cm[l31], l1 = cm[32 + l31];
        const float M  = fmaxf(m_run, m1);
        const float a0 = exp2f(m_run - M);
        const float a1 = exp2f(m1 - M);
        const float inv = 1.0f / (lsum*a0 + l1*a1);
        #pragma unroll
        for (int r = 0; r < 16; ++r) {
            const int qr = (r&3) + 8*(r>>2) + 4*hi;
            const float a0r = __shfl(a0, qr, 64);
            const float a1r = __shfl(a1, qr, 64);
            const float ivr = __shfl(inv, qr, 64);
            float* op = O + (size_t)(q0 + qr)*QD + h*HD + l31;
            #pragma unroll
            for (int dc = 0; dc < 4; ++dc) {
                const float merged = oa[dc][r]*a0r + cO[qr*128 + dc*32 + l31]*a1r;
                op[dc*32] = merged * ivr;
            }
        }
    }
}

// ===================== fallback: self-staging (no workspace), verified R1 =====================
__global__ __launch_bounds__(256) void gqa_attn_fwd_fb(
        const float* __restrict__ Q, const float* __restrict__ K,
        const float* __restrict__ V, float* __restrict__ O)
{
    __shared__ unsigned short K_lds[32*128];
    __shared__ unsigned short V_lds[32*128];

    const int tid  = threadIdx.x;
    const int wv   = tid >> 6;
    const int lane = tid & 63;
    const int lo   = lane & 15;
    const int g    = lane >> 4;

    const int bid = blockIdx.x;
    const int h   = bid % NH;
    const int qt  = (SEQL/64 - 1) - bid / NH;
    const int q0  = qt * 64;
    const int kvh = h / GRP;

    bf16x8 qf[4];
    {
        const int qrow = q0 + wv*16 + lo;
        const float* qp = Q + (size_t)qrow*QD + h*HD + g*8;
        #pragma unroll
        for (int c = 0; c < 4; ++c) {
            const f32x4* p = reinterpret_cast<const f32x4*>(qp + c*32);
            f32x4 a = p[0], b = p[1];
            bf16x8 f;
            f[0]=(short)f2bf(a[0]*SCL); f[1]=(short)f2bf(a[1]*SCL);
            f[2]=(short)f2bf(a[2]*SCL); f[3]=(short)f2bf(a[3]*SCL);
            f[4]=(short)f2bf(b[0]*SCL); f[5]=(short)f2bf(b[1]*SCL);
            f[6]=(short)f2bf(b[2]*SCL); f[7]=(short)f2bf(b[3]*SCL);
            qf[c] = f;
        }
    }

    f32x4 oa[8];
    #pragma unroll
    for (int i = 0; i < 8; ++i) oa[i] = (f32x4){0.f, 0.f, 0.f, 0.f};
    float m_run = -1e30f, lsum = 0.f;

    const int qmax_w = q0 + wv*16 + 15;
    const int nt = q0/32 + 2;

    for (int t = 0; t < nt; ++t) {
        const int kvb = t*32;
        __syncthreads();
        {
            const int row = tid >> 3;
            const int dc  = (tid & 7) * 16;
            const float* kp = K + (size_t)(kvb+row)*KD + kvh*HD + dc;
            const f32x4* kp4 = reinterpret_cast<const f32x4*>(kp);
            f32x4 a0 = kp4[0], a1 = kp4[1], a2 = kp4[2], a3 = kp4[3];
            bf16x8 t0, t1;
            t0[0]=(short)f2bf(a0[0]); t0[1]=(short)f2bf(a0[1]); t0[2]=(short)f2bf(a0[2]); t0[3]=(short)f2bf(a0[3]);
            t0[4]=(short)f2bf(a1[0]); t0[5]=(short)f2bf(a1[1]); t0[6]=(short)f2bf(a1[2]); t0[7]=(short)f2bf(a1[3]);
            t1[0]=(short)f2bf(a2[0]); t1[1]=(short)f2bf(a2[1]); t1[2]=(short)f2bf(a2[2]); t1[3]=(short)f2bf(a2[3]);
            t1[4]=(short)f2bf(a3[0]); t1[5]=(short)f2bf(a3[1]); t1[6]=(short)f2bf(a3[2]); t1[7]=(short)f2bf(a3[3]);
            char* kl = reinterpret_cast<char*>(K_lds);
            const int byte = row*256 + dc*2;
            const int swzw = (row & 7) << 4;
            *reinterpret_cast<bf16x8*>(kl + ((byte)      ^ swzw)) = t0;
            *reinterpret_cast<bf16x8*>(kl + ((byte + 16) ^ swzw)) = t1;
        }
        {
            const int kv0   = (tid >> 4) * 2;
            const int dbase = (tid & 15) * 8;
            const float* vp = V + (size_t)(kvb+kv0)*KD + kvh*HD + dbase;
            const f32x4* v0 = reinterpret_cast<const f32x4*>(vp);
            const f32x4* v1 = reinterpret_cast<const f32x4*>(vp + KD);
            f32x4 a0 = v0[0], a1 = v0[1], b0 = v1[0], b1 = v1[1];
            unsigned int* vf = reinterpret_cast<unsigned int*>(V_lds);
            #pragma unroll
            for (int i = 0; i < 8; ++i) {
                float x0 = (i < 4) ? a0[i] : a1[i-4];
                float x1 = (i < 4) ? b0[i] : b1[i-4];
                unsigned int pkv = f2bf(x0) | (f2bf(x1) << 16);
                const int d  = dbase + i;
                const int db = d >> 4, dl = d & 15;
                const int slot = (kv0 >> 3) ^ (d & 3) ^ (db & 3);
                const int byte = db*1024 + dl*64 + slot*16 + (kv0 & 7)*2;
                vf[byte >> 2] = pkv;
            }
        }
        __syncthreads();

        if (kvb > qmax_w) continue;

        f32x4 s0 = {0,0,0,0}, s1 = {0,0,0,0};
        {
            const char* kl = reinterpret_cast<const char*>(K_lds);
            const int r0 = lo, r1 = lo + 16;
            const int sw0 = (r0 & 7) << 4, sw1 = (r1 & 7) << 4;
            #pragma unroll
            for (int c = 0; c < 4; ++c) {
                bf16x8 ka = *reinterpret_cast<const bf16x8*>(kl + ((r0*256 + c*64 + g*16) ^ sw0));
                bf16x8 kb = *reinterpret_cast<const bf16x8*>(kl + ((r1*256 + c*64 + g*16) ^ sw1));
                s0 = __builtin_amdgcn_mfma_f32_16x16x32_bf16(ka, qf[c], s0, 0, 0, 0);
                s1 = __builtin_amdgcn_mfma_f32_16x16x32_bf16(kb, qf[c], s1, 0, 0, 0);
            }
        }

        const int qabs = q0 + wv*16 + lo;
        if (kvb + 31 > q0 + wv*16) {
            #pragma unroll
            for (int r = 0; r < 4; ++r) {
                if (kvb + 4*g + r      > qabs) s0[r] = -1e30f;
                if (kvb + 16 + 4*g + r > qabs) s1[r] = -1e30f;
            }
        }

        float pmax = fmaxf(fmaxf(fmaxf(s0[0],s0[1]), fmaxf(s0[2],s0[3])),
                           fmaxf(fmaxf(s1[0],s1[1]), fmaxf(s1[2],s1[3])));
        pmax = fmaxf(pmax, __shfl_xor(pmax, 16));
        pmax = fmaxf(pmax, __shfl_xor(pmax, 32));
        const float m_new = fmaxf(m_run, pmax);
        const float alpha = exp2f(m_run - m_new);
        float p0[4], p1[4];
        float psum = 0.f;
        #pragma unroll
        for (int r = 0; r < 4; ++r) {
            p0[r] = exp2f(s0[r] - m_new); psum += p0[r];
            p1[r] = exp2f(s1[r] - m_new); psum += p1[r];
        }
        psum += __shfl_xor(psum, 16);
        psum += __shfl_xor(psum, 32);
        lsum = lsum * alpha + psum;
        m_run = m_new;

        unsigned int pk0[2], pk1[2];
        pk0[0] = f2bf(p0[0]) | (f2bf(p0[1]) << 16);
        pk0[1] = f2bf(p0[2]) | (f2bf(p0[3]) << 16);
        pk1[0] = f2bf(p1[0]) | (f2bf(p1[1]) << 16);
        pk1[1] = f2bf(p1[2]) | (f2bf(p1[3]) << 16);

        i32x4 pav;
        #pragma unroll
        for (int pp = 0; pp < 4; ++pp) {
            const int src = lo + ((2*g + (pp >> 1)) & 3) * 16;
            const int v0s = __shfl((int)pk0[pp & 1], src, 64);
            const int v1s = __shfl((int)pk1[pp & 1], src, 64);
            pav[pp] = (g < 2) ? v0s : v1s;
        }
        const bf16x8 paf = __builtin_bit_cast(bf16x8, pav);

        float al[4];
        #pragma unroll
        for (int r = 0; r < 4; ++r) al[r] = __shfl(alpha, 4*g + r, 64);
        #pragma unroll
        for (int db = 0; db < 8; ++db) {
            oa[db][0] *= al[0]; oa[db][1] *= al[1];
            oa[db][2] *= al[2]; oa[db][3] *= al[3];
        }

        const char* vl = reinterpret_cast<const char*>(V_lds);
        #pragma unroll
        for (int db = 0; db < 8; ++db) {
            const int slot = g ^ (lo & 3) ^ (db & 3);
            bf16x8 vfr = *reinterpret_cast<const bf16x8*>(vl + db*1024 + lo*64 + slot*16);
            oa[db] = __builtin_amdgcn_mfma_f32_16x16x32_bf16(paf, vfr, oa[db], 0, 0, 0);
        }
    }

    float li[4];
    #pragma unroll
    for (int r = 0; r < 4; ++r) li[r] = 1.0f / __shfl(lsum, 4*g + r, 64);
    #pragma unroll
    for (int db = 0; db < 8; ++db) {
        #pragma unroll
        for (int r = 0; r < 4; ++r) {
            O[(size_t)(q0 + wv*16 + 4*g + r)*QD + h*HD + db*16 + lo] = oa[db][r] * li[r];
        }
    }
}

extern "C" void kernel_launch(void* const* d_in, const int* in_sizes, int n_in,
                              void* d_out, int out_size, void* d_ws, size_t ws_size,
                              hipStream_t stream) {
    const float* q = (const float*)d_in[0];
    const float* k = (const float*)d_in[1];
    const float* v = (const float*)d_in[2];
    float* out = (float*)d_out;
    (void)in_sizes; (void)n_in; (void)out_size;

    if (ws_size >= WS_NEED && d_ws != nullptr) {
        char* kw = (char*)d_ws;
        char* vw = kw + (size_t)NKV * NT_KV * TILE_B;
        conv_k<<<dim3(512), dim3(256), 0, stream>>>(k, kw);
        conv_v<<<dim3(512), dim3(256), 0, stream>>>(v, vw);
        gqa_attn_fwd<<<dim3((SEQL/32)*NH), dim3(128), 0, stream>>>(q, kw, vw, out);
    } else {
        gqa_attn_fwd_fb<<<dim3((SEQL/64)*NH), dim3(256), 0, stream>>>(q, k, v, out);
    }
}